// Round 1
// baseline (42.523 us; speedup 1.0000x reference)
//
#include <hip/hip_runtime.h>

// B=524288 independent attentions over [S=10, D=6].
// out[b,q] = sum_k softmax_k(Q_q . K_k) * vsum[k]
// Restructured: score[q,k] = x_q . (G x_k) + w.x_k   (q-constant terms cancel in softmax)
//   G[d][d'] = sum_e Wq[e][d] Wk[e][d']
//   w[d']    = sum_e bq[e]  Wk[e][d']
//   vsum[k]  = x_k . wvs + bvs,  wvs[d] = sum_e Wv[e][d],  bvs = sum_e bv[e]
// ws layout (floats): [0..35] G row-major, [36..41] w, [42..47] wvs, [48] bvs

#define NB 524288
#define S 10
#define D 6

__global__ void precompute_kernel(const float* __restrict__ Wk, const float* __restrict__ bk,
                                  const float* __restrict__ Wq, const float* __restrict__ bq,
                                  const float* __restrict__ Wv, const float* __restrict__ bv,
                                  float* __restrict__ ws) {
    int t = threadIdx.x;
    if (t < 36) {
        int d = t / 6, dp = t % 6;
        float g = 0.f;
        for (int e = 0; e < D; ++e) g += Wq[e * D + d] * Wk[e * D + dp];
        ws[t] = g;
    } else if (t < 42) {
        int dp = t - 36;
        float s = 0.f;
        for (int e = 0; e < D; ++e) s += bq[e] * Wk[e * D + dp];
        ws[t] = s;
    } else if (t < 48) {
        int d = t - 42;
        float s = 0.f;
        for (int e = 0; e < D; ++e) s += Wv[e * D + d];
        ws[t] = s;
    } else if (t == 48) {
        float s = 0.f;
        for (int e = 0; e < D; ++e) s += bv[e];
        ws[t] = s;
    }
}

__global__ __launch_bounds__(256) void attn_kernel(const float* __restrict__ x,
                                                   const float* __restrict__ ws,
                                                   float* __restrict__ out) {
    int b = blockIdx.x * blockDim.x + threadIdx.x;
    if (b >= NB) return;

    // Uniform constants (address independent of lane -> s_load / SGPR resident)
    float G[36], w[6], wvs[6];
    #pragma unroll
    for (int i = 0; i < 36; ++i) G[i] = ws[i];
    #pragma unroll
    for (int i = 0; i < 6; ++i) w[i] = ws[36 + i];
    #pragma unroll
    for (int i = 0; i < 6; ++i) wvs[i] = ws[42 + i];
    float bvs = ws[48];

    // Load this batch's x: 60 floats, 16B-aligned (240 bytes) -> 15 float4
    const float4* xp = (const float4*)(x + (size_t)b * (S * D));
    float xv[S * D];
    #pragma unroll
    for (int i = 0; i < 15; ++i) {
        float4 v = xp[i];
        xv[4 * i + 0] = v.x;
        xv[4 * i + 1] = v.y;
        xv[4 * i + 2] = v.z;
        xv[4 * i + 3] = v.w;
    }

    // z[k] = G x_k, a[k] = w.x_k, vs[k] = wvs.x_k + bvs
    float z[S * D], a[S], vs[S];
    #pragma unroll
    for (int k = 0; k < S; ++k) {
        #pragma unroll
        for (int d = 0; d < D; ++d) {
            float zz = 0.f;
            #pragma unroll
            for (int dp = 0; dp < D; ++dp) zz += G[d * 6 + dp] * xv[k * D + dp];
            z[k * D + d] = zz;
        }
        float ak = 0.f, vk = bvs;
        #pragma unroll
        for (int dp = 0; dp < D; ++dp) {
            ak += w[dp] * xv[k * D + dp];
            vk += wvs[dp] * xv[k * D + dp];
        }
        a[k] = ak;
        vs[k] = vk;
    }

    // scores + softmax + weighted vsum (no max-subtraction: |s| <~ 6, exp safe)
    float o[S];
    #pragma unroll
    for (int q = 0; q < S; ++q) {
        float num = 0.f, den = 0.f;
        #pragma unroll
        for (int k = 0; k < S; ++k) {
            float s = a[k];
            #pragma unroll
            for (int d = 0; d < D; ++d) s += xv[q * D + d] * z[k * D + d];
            float e = __expf(s);
            den += e;
            num += e * vs[k];
        }
        o[q] = num * __builtin_amdgcn_rcpf(den);
    }

    // 40B output per thread, 8B-aligned -> 5 float2 stores
    float2* op = (float2*)(out + (size_t)b * S);
    #pragma unroll
    for (int i = 0; i < 5; ++i) op[i] = make_float2(o[2 * i + 0], o[2 * i + 1]);
}

extern "C" void kernel_launch(void* const* d_in, const int* in_sizes, int n_in,
                              void* d_out, int out_size, void* d_ws, size_t ws_size,
                              hipStream_t stream) {
    const float* x  = (const float*)d_in[0];
    const float* Wk = (const float*)d_in[1];
    const float* bk = (const float*)d_in[2];
    const float* Wq = (const float*)d_in[3];
    const float* bq = (const float*)d_in[4];
    const float* Wv = (const float*)d_in[5];
    const float* bv = (const float*)d_in[6];
    float* out = (float*)d_out;
    float* ws  = (float*)d_ws;

    precompute_kernel<<<1, 64, 0, stream>>>(Wk, bk, Wq, bq, Wv, bv, ws);
    attn_kernel<<<NB / 256, 256, 0, stream>>>(x, ws, out);
}